// Round 9
// baseline (13735.217 us; speedup 1.0000x reference)
//
#include <hip/hip_runtime.h>

typedef __attribute__((ext_vector_type(8))) short short8v;
typedef __attribute__((ext_vector_type(4))) float f32x4;

#define NB 1024
#define NS 200
#define ND 512
#define NG 1536
#define NM 204800   // NB*NS
#define NFF 256

__device__ __forceinline__ float bf2f(unsigned short u){
  union { unsigned u; float f; } v; v.u = ((unsigned)u) << 16; return v.f;
}
__device__ __forceinline__ unsigned short f2bf(float f){
  union { float f; unsigned u; } v; v.f = f;
  unsigned r = v.u + 0x7fffu + ((v.u >> 16) & 1u);
  return (unsigned short)(r >> 16);
}
__device__ __forceinline__ float sigm(float x){ return 1.f / (1.f + __expf(-x)); }
__device__ __forceinline__ float tanhfast(float x){ return 1.f - 2.f / (1.f + __expf(2.f * x)); }

// ---------------- pack W (N x K, row-major, f32) into MFMA B-frag order ----------------
__global__ void k_prepack(const float* __restrict__ W, unsigned short* __restrict__ out,
                          int ld, int coloff, int ntiles){
  int gid = blockIdx.x * 256 + threadIdx.x;
  if (gid >= ntiles * 1024) return;
  int ntile = gid >> 10; int rem = gid & 1023;
  int kk = rem >> 6; int lane = rem & 63;
  int c = ntile * 16 + (lane & 15);
  int k0 = kk * 32 + (lane >> 4) * 8;
  const float* s = W + (size_t)c * ld + coloff + k0;
  uint4 v;
  v.x = (unsigned)f2bf(s[0]) | ((unsigned)f2bf(s[1]) << 16);
  v.y = (unsigned)f2bf(s[2]) | ((unsigned)f2bf(s[3]) << 16);
  v.z = (unsigned)f2bf(s[4]) | ((unsigned)f2bf(s[5]) << 16);
  v.w = (unsigned)f2bf(s[6]) | ((unsigned)f2bf(s[7]) << 16);
  *(uint4*)(out + (size_t)gid * 8) = v;
}

// ---------------- tvec[b][f] = b_fc[f] + sum_d target[b][d] * W_fc[f][512+d] ----------------
__global__ void k_tvec(const float* __restrict__ target, const float* __restrict__ Wfc,
                       const float* __restrict__ bfc, float* __restrict__ tvec){
  __shared__ float tg[4][ND];
  int bb = blockIdx.x;
  int tid = threadIdx.x;
  for (int idx = tid; idx < 4 * ND; idx += 256){
    int j = idx >> 9, d = idx & 511;
    tg[j][d] = target[(size_t)(bb * 4 + j) * ND + d];
  }
  __syncthreads();
  const float* wrow = Wfc + (size_t)tid * 1024 + 512;
  float a0 = 0, a1 = 0, a2 = 0, a3 = 0;
  for (int d = 0; d < ND; ++d){
    float wv = wrow[d];
    a0 += tg[0][d] * wv; a1 += tg[1][d] * wv; a2 += tg[2][d] * wv; a3 += tg[3][d] * wv;
  }
  float bias = bfc[tid];
  tvec[(size_t)(bb * 4 + 0) * NFF + tid] = a0 + bias;
  tvec[(size_t)(bb * 4 + 1) * NFF + tid] = a1 + bias;
  tvec[(size_t)(bb * 4 + 2) * NFF + tid] = a2 + bias;
  tvec[(size_t)(bb * 4 + 3) * NFF + tid] = a3 + bias;
}

// ---------------- gx = history(f32) @ W_ih^T + bias, output bf16 (NM x 1536) ----------------
// bias folds b_ih (all gates) + b_hh (r,z gates only; n-gate b_hh multiplies r in the GRU).
__global__ __launch_bounds__(256) void k_gemm_gx(const float* __restrict__ Af,
                                                 const unsigned short* __restrict__ Bpk,
                                                 const float* __restrict__ bih,
                                                 const float* __restrict__ bhh,
                                                 unsigned short* __restrict__ gx){
  __shared__ unsigned short As[128 * 64];
  int tid = threadIdx.x; int lane = tid & 63; int wid = tid >> 6;
  int wm = wid >> 1, wn = wid & 1;
  int Nb = blockIdx.x, Mb = blockIdx.y;
  const float* Abase = Af + (size_t)Mb * 128 * ND;
  const short8v* Bp = (const short8v*)Bpk;
  f32x4 acc[4][4];
  #pragma unroll
  for (int i = 0; i < 4; ++i)
    #pragma unroll
    for (int j = 0; j < 4; ++j) acc[i][j] = (f32x4){0.f, 0.f, 0.f, 0.f};

  for (int kc = 0; kc < 8; ++kc){
    __syncthreads();
    #pragma unroll
    for (int pass = 0; pass < 4; ++pass){
      int idx = pass * 256 + tid; int r = idx >> 3, ch = idx & 7;
      const float* src = Abase + (size_t)r * ND + kc * 64 + ch * 8;
      float4 f0 = *(const float4*)src;
      float4 f1 = *(const float4*)(src + 4);
      uint4 v;
      v.x = (unsigned)f2bf(f0.x) | ((unsigned)f2bf(f0.y) << 16);
      v.y = (unsigned)f2bf(f0.z) | ((unsigned)f2bf(f0.w) << 16);
      v.z = (unsigned)f2bf(f1.x) | ((unsigned)f2bf(f1.y) << 16);
      v.w = (unsigned)f2bf(f1.z) | ((unsigned)f2bf(f1.w) << 16);
      *(uint4*)&As[r * 64 + ch * 8] = v;
    }
    __syncthreads();
    #pragma unroll
    for (int i = 0; i < 2; ++i){
      short8v a[4];
      #pragma unroll
      for (int mt = 0; mt < 4; ++mt)
        a[mt] = *(const short8v*)&As[(wm * 64 + mt * 16 + (lane & 15)) * 64 + i * 32 + (lane >> 4) * 8];
      #pragma unroll
      for (int nt = 0; nt < 4; ++nt){
        short8v b = Bp[((size_t)(Nb * 8 + wn * 4 + nt) * 16 + (kc * 2 + i)) * 64 + lane];
        #pragma unroll
        for (int mt = 0; mt < 4; ++mt)
          acc[mt][nt] = __builtin_amdgcn_mfma_f32_16x16x32_bf16(a[mt], b, acc[mt][nt], 0, 0, 0);
      }
    }
  }
  #pragma unroll
  for (int mt = 0; mt < 4; ++mt){
    #pragma unroll
    for (int nt = 0; nt < 4; ++nt){
      int gcol = Nb * 128 + wn * 64 + nt * 16 + (lane & 15);
      float bv = bih[gcol] + (gcol < 1024 ? bhh[gcol] : 0.f);
      #pragma unroll
      for (int r = 0; r < 4; ++r){
        int grow = Mb * 128 + wm * 64 + mt * 16 + (lane >> 4) * 4 + r;
        gx[(size_t)grow * NG + gcol] = f2bf(acc[mt][nt][r] + bv);
      }
    }
  }
}

// ---------------- GRU recurrence v8: block-local, zero inter-block sync ----------------
// 256 blocks x 1024 threads; each block owns 4 batches and the FULL 512-col hidden state.
// Full W_hh resident across the CU register file: 16 waves x 384 regs (wf[6][16]) = 1.57MB.
// Per step: MFMA (M=4 useful of 16) -> gpre LDS redistribution -> all-thread activation
// -> LDS re-gather into A-frag layout. 3 intra-block barriers; no atomics anywhere.
__global__ __launch_bounds__(1024, 1) void k_gru8(const unsigned short* __restrict__ gx,
                                                  const unsigned short* __restrict__ Wpk,
                                                  const float* __restrict__ bhh,
                                                  unsigned short* __restrict__ gout){
  __shared__ unsigned short hfrag[2][16 * 512];   // A-frag layout, batch=(l&3), 2 parities
  __shared__ float gpre[NG][4];                    // gate pre-acts [gatecol][batch]
  __shared__ unsigned short hplain[4][520];        // plain h for re-gather (+pad)
  __shared__ float bhn_s[ND];

  int tid = threadIdx.x; int lane = tid & 63; int w = tid >> 6;   // 16 waves
  int b0 = blockIdx.x * 4;

  // resident W_hh: wave w owns gate-col tiles w*6 .. w*6+5
  short8v wf[6][16];
  const short8v* Wp = (const short8v*)Wpk;
  #pragma unroll
  for (int nt = 0; nt < 6; ++nt){
    int ntg = w * 6 + nt;
    #pragma unroll
    for (int kk = 0; kk < 16; ++kk)
      wf[nt][kk] = Wp[((size_t)ntg * 16 + kk) * 64 + lane];
  }
  if (tid < ND) bhn_s[tid] = bhh[1024 + tid];
  // zero parity-0 frag (1024 threads x 16B)
  ((uint4*)hfrag[0])[tid] = (uint4){0u, 0u, 0u, 0u};

  // activation ownership: items (ba, c) and (ba+2, c)
  int c = tid & 511; int ba = tid >> 9;
  float h0 = 0.f, h1 = 0.f;
  // preload gx for t=0
  unsigned short cx[6];
  {
    const unsigned short* g0 = gx + ((size_t)(b0 + ba) * NS + 0) * NG + c;
    const unsigned short* g1 = gx + ((size_t)(b0 + ba + 2) * NS + 0) * NG + c;
    cx[0] = g0[0]; cx[1] = g0[512]; cx[2] = g0[1024];
    cx[3] = g1[0]; cx[4] = g1[512]; cx[5] = g1[1024];
  }
  __syncthreads();

  #pragma unroll 1
  for (int t = 0; t < NS; ++t){
    int par = t & 1;
    const unsigned short* hr = hfrag[par];
    f32x4 acc[6];
    #pragma unroll
    for (int nt = 0; nt < 6; ++nt) acc[nt] = (f32x4){0.f, 0.f, 0.f, 0.f};
    #pragma unroll
    for (int kc = 0; kc < 16; ++kc){
      short8v a = *(const short8v*)&hr[kc * 512 + lane * 8];
      #pragma unroll
      for (int nt = 0; nt < 6; ++nt)
        acc[nt] = __builtin_amdgcn_mfma_f32_16x16x32_bf16(a, wf[nt][kc], acc[nt], 0, 0, 0);
    }
    // C rows 0-3 (= batches 0-3) live in lanes 0-15, regs 0-3
    if (lane < 16){
      #pragma unroll
      for (int nt = 0; nt < 6; ++nt)
        *(f32x4*)&gpre[w * 96 + nt * 16 + lane][0] = acc[nt];
    }
    __syncthreads();   // B1: gpre complete
    // issue gx prefetch for t+1 (flies during act + barriers + next MFMA)
    unsigned short nx[6];
    if (t + 1 < NS){
      const unsigned short* g0 = gx + ((size_t)(b0 + ba) * NS + (t + 1)) * NG + c;
      const unsigned short* g1 = gx + ((size_t)(b0 + ba + 2) * NS + (t + 1)) * NG + c;
      nx[0] = g0[0]; nx[1] = g0[512]; nx[2] = g0[1024];
      nx[3] = g1[0]; nx[4] = g1[512]; nx[5] = g1[1024];
    }
    // activation (bias note: r,z biases folded into gx; n-gate bhh multiplies r)
    float bhn = bhn_s[c];
    float r0 = sigm(bf2f(cx[0]) + gpre[c][ba]);
    float z0 = sigm(bf2f(cx[1]) + gpre[512 + c][ba]);
    float n0 = tanhfast(bf2f(cx[2]) + r0 * (gpre[1024 + c][ba] + bhn));
    h0 = n0 + z0 * (h0 - n0);
    float r1 = sigm(bf2f(cx[3]) + gpre[c][ba + 2]);
    float z1 = sigm(bf2f(cx[4]) + gpre[512 + c][ba + 2]);
    float n1 = tanhfast(bf2f(cx[5]) + r1 * (gpre[1024 + c][ba + 2] + bhn));
    h1 = n1 + z1 * (h1 - n1);
    unsigned short u0 = f2bf(h0), u1 = f2bf(h1);
    hplain[ba][c] = u0; hplain[ba + 2][c] = u1;
    gout[((size_t)(b0 + ba) * NS + t) * ND + c] = u0;
    gout[((size_t)(b0 + ba + 2) * NS + t) * ND + c] = u1;
    __syncthreads();   // B2: hplain complete, gpre consumed
    if (t + 1 < NS){
      // re-gather into A-frag layout: wave w fills k-frag kc=w; slot lane holds batch lane&3
      uint4 v = *(const uint4*)&hplain[lane & 3][w * 32 + (lane >> 4) * 8];
      *(uint4*)&hfrag[par ^ 1][w * 512 + lane * 8] = v;
    }
    __syncthreads();   // B3: frag ready for next MFMA
    #pragma unroll
    for (int i = 0; i < 6; ++i) cx[i] = nx[i];
  }
}

// ---------------- pre/GELU/scores fused GEMM: (NM x 512) @ Wg^T (256) ----------------
__global__ __launch_bounds__(512) void k_gemm_s4(const unsigned short* __restrict__ A,
                                                 const unsigned short* __restrict__ Bpk,
                                                 const float* __restrict__ tvec,
                                                 const float* __restrict__ Wsc,
                                                 const float* __restrict__ bsc,
                                                 float* __restrict__ scores){
  __shared__ unsigned short As[128 * 64];
  __shared__ float spart[4][128];
  int tid = threadIdx.x; int lane = tid & 63; int wid = tid >> 6;
  int wm = wid >> 2, wn = wid & 3;
  int Mb = blockIdx.x;
  const unsigned short* Abase = A + (size_t)Mb * 128 * ND;
  const short8v* Bp = (const short8v*)Bpk;
  f32x4 acc[4][4];
  #pragma unroll
  for (int i = 0; i < 4; ++i)
    #pragma unroll
    for (int j = 0; j < 4; ++j) acc[i][j] = (f32x4){0.f, 0.f, 0.f, 0.f};

  for (int kc = 0; kc < 8; ++kc){
    __syncthreads();
    #pragma unroll
    for (int pass = 0; pass < 2; ++pass){
      int idx = pass * 512 + tid; int r = idx >> 3, ch = idx & 7;
      uint4 v = *(const uint4*)(Abase + (size_t)r * ND + kc * 64 + ch * 8);
      *(uint4*)&As[r * 64 + ch * 8] = v;
    }
    __syncthreads();
    #pragma unroll
    for (int i = 0; i < 2; ++i){
      short8v a[4];
      #pragma unroll
      for (int mt = 0; mt < 4; ++mt)
        a[mt] = *(const short8v*)&As[(wm * 64 + mt * 16 + (lane & 15)) * 64 + i * 32 + (lane >> 4) * 8];
      #pragma unroll
      for (int nt = 0; nt < 4; ++nt){
        short8v b = Bp[((size_t)(wn * 4 + nt) * 16 + (kc * 2 + i)) * 64 + lane];
        #pragma unroll
        for (int mt = 0; mt < 4; ++mt)
          acc[mt][nt] = __builtin_amdgcn_mfma_f32_16x16x32_bf16(a[mt], b, acc[mt][nt], 0, 0, 0);
      }
    }
  }
  #pragma unroll
  for (int mt = 0; mt < 4; ++mt){
    #pragma unroll
    for (int r = 0; r < 4; ++r){
      int rowl = wm * 64 + mt * 16 + (lane >> 4) * 4 + r;
      unsigned grow = (unsigned)(Mb * 128 + rowl);
      unsigned bidx = grow / 200u;
      float rowsum = 0.f;
      #pragma unroll
      for (int nt = 0; nt < 4; ++nt){
        int gcol = wn * 64 + nt * 16 + (lane & 15);
        float pre = acc[mt][nt][r] + tvec[(size_t)bidx * NFF + gcol];
        float g = 0.5f * pre * (1.f + erff(pre * 0.70710678118654752f));
        rowsum += g * Wsc[gcol];
      }
      rowsum += __shfl_xor(rowsum, 1, 64);
      rowsum += __shfl_xor(rowsum, 2, 64);
      rowsum += __shfl_xor(rowsum, 4, 64);
      rowsum += __shfl_xor(rowsum, 8, 64);
      if ((lane & 15) == 0) spart[wn][rowl] = rowsum;
    }
  }
  __syncthreads();
  if (tid < 128){
    float s = spart[0][tid] + spart[1][tid] + spart[2][tid] + spart[3][tid] + bsc[0];
    scores[(size_t)Mb * 128 + tid] = s;
  }
}

// ---------------- softmax over S + weighted pool + concat output ----------------
__global__ void k_out(const float* __restrict__ scores, const unsigned short* __restrict__ gout,
                      const float* __restrict__ target, float* __restrict__ out){
  int b = blockIdx.x; int tid = threadIdx.x;
  __shared__ float sw[NS];
  __shared__ float red[4];
  float v = (tid < NS) ? scores[(size_t)b * NS + tid] : -3.0e38f;
  float m = v;
  #pragma unroll
  for (int off = 32; off >= 1; off >>= 1) m = fmaxf(m, __shfl_xor(m, off, 64));
  if ((tid & 63) == 0) red[tid >> 6] = m;
  __syncthreads();
  m = fmaxf(fmaxf(red[0], red[1]), fmaxf(red[2], red[3]));
  float e = (tid < NS) ? __expf(v - m) : 0.f;
  if (tid < NS) sw[tid] = e;
  float su = e;
  #pragma unroll
  for (int off = 32; off >= 1; off >>= 1) su += __shfl_xor(su, off, 64);
  __syncthreads();
  if ((tid & 63) == 0) red[tid >> 6] = su;
  __syncthreads();
  float inv = 1.f / (red[0] + red[1] + red[2] + red[3]);
  int d0 = tid * 2;
  float a0 = 0.f, a1 = 0.f;
  const unsigned short* gbase = gout + (size_t)b * NS * ND + d0;
  for (int s = 0; s < NS; ++s){
    unsigned u = *(const unsigned*)(gbase + (size_t)s * ND);
    float wgt = sw[s];
    a0 += wgt * bf2f((unsigned short)(u & 0xffffu));
    a1 += wgt * bf2f((unsigned short)(u >> 16));
  }
  out[(size_t)b * 1024 + d0] = a0 * inv;
  out[(size_t)b * 1024 + d0 + 1] = a1 * inv;
  float2 tv = *(const float2*)(target + (size_t)b * ND + d0);
  out[(size_t)b * 1024 + 512 + d0] = tv.x;
  out[(size_t)b * 1024 + 512 + d0 + 1] = tv.y;
}

extern "C" void kernel_launch(void* const* d_in, const int* in_sizes, int n_in,
                              void* d_out, int out_size, void* d_ws, size_t ws_size,
                              hipStream_t stream) {
  const float* target  = (const float*)d_in[0];
  const float* history = (const float*)d_in[1];
  const float* W_ih    = (const float*)d_in[2];
  const float* W_hh    = (const float*)d_in[3];
  const float* b_ih    = (const float*)d_in[4];
  const float* b_hh    = (const float*)d_in[5];
  const float* W_fc    = (const float*)d_in[6];
  const float* b_fc    = (const float*)d_in[7];
  const float* W_sc    = (const float*)d_in[8];
  const float* b_sc    = (const float*)d_in[9];

  char* ws = (char*)d_ws;
  size_t off = 0;
  unsigned short* gx     = (unsigned short*)(ws + off); off += 629145600ull;  // NM*1536 bf16
  unsigned short* gout   = (unsigned short*)(ws + off); off += 209715200ull;  // NM*512 bf16
  unsigned short* wih_pk = (unsigned short*)(ws + off); off += 1572864ull;
  unsigned short* whh_pk = (unsigned short*)(ws + off); off += 1572864ull;
  unsigned short* wg_pk  = (unsigned short*)(ws + off); off += 262144ull;
  float*          tvec   = (float*)(ws + off);          off += 1048576ull;
  float*          scores = (float*)(ws + off);          off += 819200ull;
  if (ws_size < off) return;
  float* outp = (float*)d_out;

  k_prepack<<<384, 256, 0, stream>>>(W_ih, wih_pk, 512, 0, 96);
  k_prepack<<<384, 256, 0, stream>>>(W_hh, whh_pk, 512, 0, 96);
  k_prepack<<<64, 256, 0, stream>>>(W_fc, wg_pk, 1024, 0, 16);
  k_tvec<<<256, 256, 0, stream>>>(target, W_fc, b_fc, tvec);
  k_gemm_gx<<<dim3(12, 1600), 256, 0, stream>>>(history, wih_pk, b_ih, b_hh, gx);
  k_gru8<<<256, 1024, 0, stream>>>(gx, whh_pk, b_hh, gout);
  k_gemm_s4<<<1600, 512, 0, stream>>>(gout, wg_pk, tvec, W_sc, b_sc, scores);
  k_out<<<1024, 256, 0, stream>>>(scores, gout, target, outp);
}

// Round 10
// 2352.226 us; speedup vs baseline: 5.8392x; 5.8392x over previous
//
#include <hip/hip_runtime.h>

typedef __attribute__((ext_vector_type(8))) short short8v;
typedef __attribute__((ext_vector_type(4))) float f32x4;

#define NB 1024
#define NS 200
#define ND 512
#define NG 1536
#define NM 204800   // NB*NS
#define NFF 256

#define GRU_P 4     // blocks per group (each owns 128 h-cols)
#define GRU_G 64    // groups (each owns 16 batches)

__device__ __forceinline__ float bf2f(unsigned short u){
  union { unsigned u; float f; } v; v.u = ((unsigned)u) << 16; return v.f;
}
__device__ __forceinline__ unsigned short f2bf(float f){
  union { float f; unsigned u; } v; v.f = f;
  unsigned r = v.u + 0x7fffu + ((v.u >> 16) & 1u);
  return (unsigned short)(r >> 16);
}
__device__ __forceinline__ float sigm(float x){ return 1.f / (1.f + __expf(-x)); }
__device__ __forceinline__ float tanhfast(float x){ return 1.f - 2.f / (1.f + __expf(2.f * x)); }

// ---------------- pack W (N x K, row-major, f32) into MFMA B-frag order ----------------
__global__ void k_prepack(const float* __restrict__ W, unsigned short* __restrict__ out,
                          int ld, int coloff, int ntiles){
  int gid = blockIdx.x * 256 + threadIdx.x;
  if (gid >= ntiles * 1024) return;
  int ntile = gid >> 10; int rem = gid & 1023;
  int kk = rem >> 6; int lane = rem & 63;
  int c = ntile * 16 + (lane & 15);
  int k0 = kk * 32 + (lane >> 4) * 8;
  const float* s = W + (size_t)c * ld + coloff + k0;
  uint4 v;
  v.x = (unsigned)f2bf(s[0]) | ((unsigned)f2bf(s[1]) << 16);
  v.y = (unsigned)f2bf(s[2]) | ((unsigned)f2bf(s[3]) << 16);
  v.z = (unsigned)f2bf(s[4]) | ((unsigned)f2bf(s[5]) << 16);
  v.w = (unsigned)f2bf(s[6]) | ((unsigned)f2bf(s[7]) << 16);
  *(uint4*)(out + (size_t)gid * 8) = v;
}

// ---------------- tvec[b][f] = b_fc[f] + sum_d target[b][d] * W_fc[f][512+d] ----------------
__global__ void k_tvec(const float* __restrict__ target, const float* __restrict__ Wfc,
                       const float* __restrict__ bfc, float* __restrict__ tvec){
  __shared__ float tg[4][ND];
  int bb = blockIdx.x;
  int tid = threadIdx.x;
  for (int idx = tid; idx < 4 * ND; idx += 256){
    int j = idx >> 9, d = idx & 511;
    tg[j][d] = target[(size_t)(bb * 4 + j) * ND + d];
  }
  __syncthreads();
  const float* wrow = Wfc + (size_t)tid * 1024 + 512;
  float a0 = 0, a1 = 0, a2 = 0, a3 = 0;
  for (int d = 0; d < ND; ++d){
    float wv = wrow[d];
    a0 += tg[0][d] * wv; a1 += tg[1][d] * wv; a2 += tg[2][d] * wv; a3 += tg[3][d] * wv;
  }
  float bias = bfc[tid];
  tvec[(size_t)(bb * 4 + 0) * NFF + tid] = a0 + bias;
  tvec[(size_t)(bb * 4 + 1) * NFF + tid] = a1 + bias;
  tvec[(size_t)(bb * 4 + 2) * NFF + tid] = a2 + bias;
  tvec[(size_t)(bb * 4 + 3) * NFF + tid] = a3 + bias;
}

// ---------------- gx = history(f32) @ W_ih^T + bias, output bf16 (NM x 1536) ----------------
// bias folds b_ih (all gates) + b_hh (r,z gates; n-gate b_hh multiplies r in the GRU).
__global__ __launch_bounds__(256) void k_gemm_gx(const float* __restrict__ Af,
                                                 const unsigned short* __restrict__ Bpk,
                                                 const float* __restrict__ bih,
                                                 const float* __restrict__ bhh,
                                                 unsigned short* __restrict__ gx){
  __shared__ unsigned short As[128 * 64];
  int tid = threadIdx.x; int lane = tid & 63; int wid = tid >> 6;
  int wm = wid >> 1, wn = wid & 1;
  int Nb = blockIdx.x, Mb = blockIdx.y;
  const float* Abase = Af + (size_t)Mb * 128 * ND;
  const short8v* Bp = (const short8v*)Bpk;
  f32x4 acc[4][4];
  #pragma unroll
  for (int i = 0; i < 4; ++i)
    #pragma unroll
    for (int j = 0; j < 4; ++j) acc[i][j] = (f32x4){0.f, 0.f, 0.f, 0.f};

  for (int kc = 0; kc < 8; ++kc){
    __syncthreads();
    #pragma unroll
    for (int pass = 0; pass < 4; ++pass){
      int idx = pass * 256 + tid; int r = idx >> 3, ch = idx & 7;
      const float* src = Abase + (size_t)r * ND + kc * 64 + ch * 8;
      float4 f0 = *(const float4*)src;
      float4 f1 = *(const float4*)(src + 4);
      uint4 v;
      v.x = (unsigned)f2bf(f0.x) | ((unsigned)f2bf(f0.y) << 16);
      v.y = (unsigned)f2bf(f0.z) | ((unsigned)f2bf(f0.w) << 16);
      v.z = (unsigned)f2bf(f1.x) | ((unsigned)f2bf(f1.y) << 16);
      v.w = (unsigned)f2bf(f1.z) | ((unsigned)f2bf(f1.w) << 16);
      *(uint4*)&As[r * 64 + ch * 8] = v;
    }
    __syncthreads();
    #pragma unroll
    for (int i = 0; i < 2; ++i){
      short8v a[4];
      #pragma unroll
      for (int mt = 0; mt < 4; ++mt)
        a[mt] = *(const short8v*)&As[(wm * 64 + mt * 16 + (lane & 15)) * 64 + i * 32 + (lane >> 4) * 8];
      #pragma unroll
      for (int nt = 0; nt < 4; ++nt){
        short8v b = Bp[((size_t)(Nb * 8 + wn * 4 + nt) * 16 + (kc * 2 + i)) * 64 + lane];
        #pragma unroll
        for (int mt = 0; mt < 4; ++mt)
          acc[mt][nt] = __builtin_amdgcn_mfma_f32_16x16x32_bf16(a[mt], b, acc[mt][nt], 0, 0, 0);
      }
    }
  }
  #pragma unroll
  for (int mt = 0; mt < 4; ++mt){
    #pragma unroll
    for (int nt = 0; nt < 4; ++nt){
      int gcol = Nb * 128 + wn * 64 + nt * 16 + (lane & 15);
      float bv = bih[gcol] + (gcol < 1024 ? bhh[gcol] : 0.f);
      #pragma unroll
      for (int r = 0; r < 4; ++r){
        int grow = Mb * 128 + wm * 64 + mt * 16 + (lane >> 4) * 4 + r;
        gx[(size_t)grow * NG + gcol] = f2bf(acc[mt][nt][r] + bv);
      }
    }
  }
}

// ---------------- GRU recurrence v9: per-wave flags, no pre-store barrier ----------------
// 64 groups x 4 blocks (512 thr, 2 waves/SIMD, 192-reg wf fits 512-reg SIMD budget).
// Producer wave nh: intra-wave LDS transpose (lgkmcnt only) -> ONE 8B agent store ->
// vmcnt drain -> per-wave flag. Consumer wave nh needs exactly 4 source-wave flags
// (2 blocks x wave-pair); polls f1, loads frag nh, polls f2, loads frag nh+8.
// End-of-step __syncthreads restores the full symmetric happens-before union
// (parity-2 overwrite race stays closed).
__global__ __launch_bounds__(512, 1) void k_gru9(const unsigned short* __restrict__ gx,
                                                 const unsigned short* __restrict__ Wpk,
                                                 const float* __restrict__ bhh,
                                                 unsigned short* __restrict__ gout,
                                                 unsigned long long* __restrict__ hx,  // [2][1024*128] u64
                                                 int* __restrict__ flags){             // [GRU_G*32] monotonic
  __shared__ unsigned short hbuf[2][16 * 512];   // [parity][16 k-frags of 1KB]
  __shared__ unsigned short hstg[16][136];       // intra-wave transpose (wave nh: cols nh*16..+16)
  int tid = threadIdx.x; int lane = tid & 63; int nh = tid >> 6;   // wave 0..7
  int bid = blockIdx.x; int g = bid & 63; int s = bid >> 6;        // group, slice
  int colg = lane & 15;
  int rowg = lane >> 4;
  int c_h = s * 128 + nh * 16 + colg;   // this lane's h column
  int b0 = g * 16;                      // group batch base
  int* gfl = flags + g * 32;            // this group's 32 wave-flags

  for (int i = tid; i < 16 * 512; i += 512) hbuf[0][i] = 0;

  // resident W_hh B-fragments: 3 gate tiles x 16 k-frags = 192 regs
  short8v wf[3][16];
  const short8v* Wp = (const short8v*)Wpk;
  #pragma unroll
  for (int gg = 0; gg < 3; ++gg){
    int ntile = gg * 32 + s * 8 + nh;
    #pragma unroll
    for (int kk = 0; kk < 16; ++kk)
      wf[gg][kk] = Wp[((size_t)ntile * 16 + kk) * 64 + lane];
  }
  float bN = bhh[1024 + c_h];   // only n-gate b_hh needed (r,z folded into gx)
  float hreg[4] = {0.f, 0.f, 0.f, 0.f};

  // per-wave poll sources: frag nh <- block nh>>2, waves {(nh&3)*2, +1};
  // frag nh+8 <- block (nh>>2)+2, same wave pair. 2 x 8B flag loads.
  int wpair = (nh & 3) * 2;
  const unsigned long long* f1 = (const unsigned long long*)&gfl[(nh >> 2) * 8 + wpair];
  const unsigned long long* f2 = (const unsigned long long*)&gfl[((nh >> 2) + 2) * 8 + wpair];

  // preload gx for t=0
  unsigned short cxr[4], cxz[4], cxn[4];
  #pragma unroll
  for (int r = 0; r < 4; ++r){
    const unsigned short* gp = gx + ((size_t)(b0 + rowg * 4 + r) * NS + 0) * NG;
    cxr[r] = gp[c_h]; cxz[r] = gp[512 + c_h]; cxn[r] = gp[1024 + c_h];
  }
  __syncthreads();

  #pragma unroll 1
  for (int t = 0; t < NS; ++t){
    int par = t & 1;
    const unsigned short* hr = hbuf[par];
    // gh = h @ Whh_slice^T
    f32x4 acc0 = (f32x4){0.f,0.f,0.f,0.f}, acc1 = acc0, acc2 = acc0;
    #pragma unroll
    for (int kc = 0; kc < 16; ++kc){
      short8v a = *(const short8v*)&hr[kc * 512 + lane * 8];
      acc0 = __builtin_amdgcn_mfma_f32_16x16x32_bf16(a, wf[0][kc], acc0, 0, 0, 0);
      acc1 = __builtin_amdgcn_mfma_f32_16x16x32_bf16(a, wf[1][kc], acc1, 0, 0, 0);
      acc2 = __builtin_amdgcn_mfma_f32_16x16x32_bf16(a, wf[2][kc], acc2, 0, 0, 0);
    }
    // activations (r,z biases pre-folded into gx); h kept f32 in regs
    unsigned short hnew[4];
    #pragma unroll
    for (int r = 0; r < 4; ++r){
      float rr = sigm(bf2f(cxr[r]) + acc0[r]);
      float zz = sigm(bf2f(cxz[r]) + acc1[r]);
      float nn = tanhfast(bf2f(cxn[r]) + rr * (acc2[r] + bN));
      float h = nn + zz * (hreg[r] - nn);
      hreg[r] = h;
      hnew[r] = f2bf(h);
    }

    if (t + 1 < NS){
      unsigned long long* hxp = hx + (size_t)par * (1024 * 128);
      // intra-wave LDS transpose of this wave's 16x16 tile (no block barrier!)
      #pragma unroll
      for (int r = 0; r < 4; ++r) hstg[rowg * 4 + r][nh * 16 + colg] = hnew[r];
      asm volatile("s_waitcnt lgkmcnt(0)" ::: "memory");
      // ONE 8B coherent store per lane: batch=lane&15, col-chunk=lane>>4
      {
        unsigned long long v8 = *(const unsigned long long*)&hstg[lane & 15][nh * 16 + (lane >> 4) * 4];
        __hip_atomic_store(&hxp[(size_t)(b0 + (lane & 15)) * 128 + s * 32 + nh * 4 + (lane >> 4)], v8,
                           __ATOMIC_RELAXED, __HIP_MEMORY_SCOPE_AGENT);
      }
      asm volatile("s_waitcnt vmcnt(0)" ::: "memory");
      if (lane == 0)
        __hip_atomic_store(&gfl[s * 8 + nh], t + 1, __ATOMIC_RELAXED, __HIP_MEMORY_SCOPE_AGENT);
      // off the publish path: gout stores + gx prefetch (fly during poll)
      #pragma unroll
      for (int r = 0; r < 4; ++r)
        gout[((size_t)(b0 + rowg * 4 + r) * NS + t) * ND + c_h] = hnew[r];
      #pragma unroll
      for (int r = 0; r < 4; ++r){
        const unsigned short* gp = gx + ((size_t)(b0 + rowg * 4 + r) * NS + (t + 1)) * NG;
        cxr[r] = gp[c_h]; cxz[r] = gp[512 + c_h]; cxn[r] = gp[1024 + c_h];
      }
      // poll f1 -> load frag nh; poll f2 -> load frag nh+8 (pipelined)
      int need = t + 1;
      unsigned long long fa;
      do {
        fa = __hip_atomic_load(f1, __ATOMIC_RELAXED, __HIP_MEMORY_SCOPE_AGENT);
      } while ((int)(fa & 0xffffffffu) < need || (int)(fa >> 32) < need);
      asm volatile("" ::: "memory");
      size_t base1 = (size_t)(b0 + (lane & 15)) * 128 + nh * 8 + (lane >> 4) * 2;
      unsigned long long u0 = __hip_atomic_load(&hxp[base1],     __ATOMIC_RELAXED, __HIP_MEMORY_SCOPE_AGENT);
      unsigned long long u1 = __hip_atomic_load(&hxp[base1 + 1], __ATOMIC_RELAXED, __HIP_MEMORY_SCOPE_AGENT);
      do {
        fa = __hip_atomic_load(f2, __ATOMIC_RELAXED, __HIP_MEMORY_SCOPE_AGENT);
      } while ((int)(fa & 0xffffffffu) < need || (int)(fa >> 32) < need);
      asm volatile("" ::: "memory");
      size_t base2 = base1 + 64;   // frag nh+8 = +8 frags * 8 u64
      unsigned long long u2 = __hip_atomic_load(&hxp[base2],     __ATOMIC_RELAXED, __HIP_MEMORY_SCOPE_AGENT);
      unsigned long long u3 = __hip_atomic_load(&hxp[base2 + 1], __ATOMIC_RELAXED, __HIP_MEMORY_SCOPE_AGENT);
      unsigned short* hw = hbuf[par ^ 1];
      { unsigned long long tmp[2] = {u0, u1}; *(uint4*)&hw[nh * 512 + lane * 8] = *(const uint4*)tmp; }
      { unsigned long long tmp[2] = {u2, u3}; *(uint4*)&hw[(nh + 8) * 512 + lane * 8] = *(const uint4*)tmp; }
      __syncthreads();   // B3: LDS ready; restores symmetric hb-union across group
    } else {
      #pragma unroll
      for (int r = 0; r < 4; ++r)
        gout[((size_t)(b0 + rowg * 4 + r) * NS + t) * ND + c_h] = hnew[r];
    }
  }
}

// ---------------- pre/GELU/scores fused GEMM: (NM x 512) @ Wg^T (256) ----------------
__global__ __launch_bounds__(512) void k_gemm_s4(const unsigned short* __restrict__ A,
                                                 const unsigned short* __restrict__ Bpk,
                                                 const float* __restrict__ tvec,
                                                 const float* __restrict__ Wsc,
                                                 const float* __restrict__ bsc,
                                                 float* __restrict__ scores){
  __shared__ unsigned short As[128 * 64];
  __shared__ float spart[4][128];
  int tid = threadIdx.x; int lane = tid & 63; int wid = tid >> 6;
  int wm = wid >> 2, wn = wid & 3;
  int Mb = blockIdx.x;
  const unsigned short* Abase = A + (size_t)Mb * 128 * ND;
  const short8v* Bp = (const short8v*)Bpk;
  f32x4 acc[4][4];
  #pragma unroll
  for (int i = 0; i < 4; ++i)
    #pragma unroll
    for (int j = 0; j < 4; ++j) acc[i][j] = (f32x4){0.f, 0.f, 0.f, 0.f};

  for (int kc = 0; kc < 8; ++kc){
    __syncthreads();
    #pragma unroll
    for (int pass = 0; pass < 2; ++pass){
      int idx = pass * 512 + tid; int r = idx >> 3, ch = idx & 7;
      uint4 v = *(const uint4*)(Abase + (size_t)r * ND + kc * 64 + ch * 8);
      *(uint4*)&As[r * 64 + ch * 8] = v;
    }
    __syncthreads();
    #pragma unroll
    for (int i = 0; i < 2; ++i){
      short8v a[4];
      #pragma unroll
      for (int mt = 0; mt < 4; ++mt)
        a[mt] = *(const short8v*)&As[(wm * 64 + mt * 16 + (lane & 15)) * 64 + i * 32 + (lane >> 4) * 8];
      #pragma unroll
      for (int nt = 0; nt < 4; ++nt){
        short8v b = Bp[((size_t)(wn * 4 + nt) * 16 + (kc * 2 + i)) * 64 + lane];
        #pragma unroll
        for (int mt = 0; mt < 4; ++mt)
          acc[mt][nt] = __builtin_amdgcn_mfma_f32_16x16x32_bf16(a[mt], b, acc[mt][nt], 0, 0, 0);
      }
    }
  }
  #pragma unroll
  for (int mt = 0; mt < 4; ++mt){
    #pragma unroll
    for (int r = 0; r < 4; ++r){
      int rowl = wm * 64 + mt * 16 + (lane >> 4) * 4 + r;
      unsigned grow = (unsigned)(Mb * 128 + rowl);
      unsigned bidx = grow / 200u;
      float rowsum = 0.f;
      #pragma unroll
      for (int nt = 0; nt < 4; ++nt){
        int gcol = wn * 64 + nt * 16 + (lane & 15);
        float pre = acc[mt][nt][r] + tvec[(size_t)bidx * NFF + gcol];
        float g = 0.5f * pre * (1.f + erff(pre * 0.70710678118654752f));
        rowsum += g * Wsc[gcol];
      }
      rowsum += __shfl_xor(rowsum, 1, 64);
      rowsum += __shfl_xor(rowsum, 2, 64);
      rowsum += __shfl_xor(rowsum, 4, 64);
      rowsum += __shfl_xor(rowsum, 8, 64);
      if ((lane & 15) == 0) spart[wn][rowl] = rowsum;
    }
  }
  __syncthreads();
  if (tid < 128){
    float s = spart[0][tid] + spart[1][tid] + spart[2][tid] + spart[3][tid] + bsc[0];
    scores[(size_t)Mb * 128 + tid] = s;
  }
}

// ---------------- softmax over S + weighted pool + concat output ----------------
__global__ void k_out(const float* __restrict__ scores, const unsigned short* __restrict__ gout,
                      const float* __restrict__ target, float* __restrict__ out){
  int b = blockIdx.x; int tid = threadIdx.x;
  __shared__ float sw[NS];
  __shared__ float red[4];
  float v = (tid < NS) ? scores[(size_t)b * NS + tid] : -3.0e38f;
  float m = v;
  #pragma unroll
  for (int off = 32; off >= 1; off >>= 1) m = fmaxf(m, __shfl_xor(m, off, 64));
  if ((tid & 63) == 0) red[tid >> 6] = m;
  __syncthreads();
  m = fmaxf(fmaxf(red[0], red[1]), fmaxf(red[2], red[3]));
  float e = (tid < NS) ? __expf(v - m) : 0.f;
  if (tid < NS) sw[tid] = e;
  float su = e;
  #pragma unroll
  for (int off = 32; off >= 1; off >>= 1) su += __shfl_xor(su, off, 64);
  __syncthreads();
  if ((tid & 63) == 0) red[tid >> 6] = su;
  __syncthreads();
  float inv = 1.f / (red[0] + red[1] + red[2] + red[3]);
  int d0 = tid * 2;
  float a0 = 0.f, a1 = 0.f;
  const unsigned short* gbase = gout + (size_t)b * NS * ND + d0;
  for (int s = 0; s < NS; ++s){
    unsigned u = *(const unsigned*)(gbase + (size_t)s * ND);
    float wgt = sw[s];
    a0 += wgt * bf2f((unsigned short)(u & 0xffffu));
    a1 += wgt * bf2f((unsigned short)(u >> 16));
  }
  out[(size_t)b * 1024 + d0] = a0 * inv;
  out[(size_t)b * 1024 + d0 + 1] = a1 * inv;
  float2 tv = *(const float2*)(target + (size_t)b * ND + d0);
  out[(size_t)b * 1024 + 512 + d0] = tv.x;
  out[(size_t)b * 1024 + 512 + d0 + 1] = tv.y;
}

extern "C" void kernel_launch(void* const* d_in, const int* in_sizes, int n_in,
                              void* d_out, int out_size, void* d_ws, size_t ws_size,
                              hipStream_t stream) {
  const float* target  = (const float*)d_in[0];
  const float* history = (const float*)d_in[1];
  const float* W_ih    = (const float*)d_in[2];
  const float* W_hh    = (const float*)d_in[3];
  const float* b_ih    = (const float*)d_in[4];
  const float* b_hh    = (const float*)d_in[5];
  const float* W_fc    = (const float*)d_in[6];
  const float* b_fc    = (const float*)d_in[7];
  const float* W_sc    = (const float*)d_in[8];
  const float* b_sc    = (const float*)d_in[9];

  char* ws = (char*)d_ws;
  size_t off = 0;
  unsigned short* gx     = (unsigned short*)(ws + off); off += 629145600ull;  // NM*1536 bf16
  unsigned short* gout   = (unsigned short*)(ws + off); off += 209715200ull;  // NM*512 bf16
  unsigned short* wih_pk = (unsigned short*)(ws + off); off += 1572864ull;
  unsigned short* whh_pk = (unsigned short*)(ws + off); off += 1572864ull;
  unsigned short* wg_pk  = (unsigned short*)(ws + off); off += 262144ull;
  float*          tvec   = (float*)(ws + off);          off += 1048576ull;
  float*          scores = (float*)(ws + off);          off += 819200ull;
  unsigned long long* hx = (unsigned long long*)(ws + off); off += 2097152ull; // [2][1024*128] u64
  int*            flags  = (int*)(ws + off);             off += 8192ull;        // [64*32] monotonic
  if (ws_size < off) return;
  float* outp = (float*)d_out;

  (void)hipMemsetAsync(flags, 0, GRU_G * 32 * sizeof(int), stream);
  k_prepack<<<384, 256, 0, stream>>>(W_ih, wih_pk, 512, 0, 96);
  k_prepack<<<384, 256, 0, stream>>>(W_hh, whh_pk, 512, 0, 96);
  k_prepack<<<64, 256, 0, stream>>>(W_fc, wg_pk, 1024, 0, 16);
  k_tvec<<<256, 256, 0, stream>>>(target, W_fc, b_fc, tvec);
  k_gemm_gx<<<dim3(12, 1600), 256, 0, stream>>>(history, wih_pk, b_ih, b_hh, gx);
  k_gru9<<<256, 512, 0, stream>>>(gx, whh_pk, b_hh, gout, hx, flags);
  k_gemm_s4<<<1600, 512, 0, stream>>>(gout, wg_pk, tvec, W_sc, b_sc, scores);
  k_out<<<1024, 256, 0, stream>>>(scores, gout, target, outp);
}